// Round 8
// baseline (205.415 us; speedup 1.0000x reference)
//
#include <hip/hip_runtime.h>
#include <hip/hip_bf16.h>

// Problem constants: x [4,32,32,16,256] -> N=65536 rows, D=256
// embeddings [256, 4096] -> D=256, K=4096
#define NROWS 65536
#define DIM   256
#define KCB   4096
#define CHUNK 32                 // codebook cols per chunk (16KB)
#define NCH   (KCB / CHUNK)      // 128 chunks
#define NBUF  4                  // buffer ring depth
#define BUFB  16384              // bytes per buffer
#define NENH_BASE (NBUF * BUFB)  // nenh f32[4096] at end of LDS (16KB)

typedef __attribute__((ext_vector_type(8))) short bf16x8;  // 8 bf16, 4 VGPRs
typedef __attribute__((ext_vector_type(4))) float f32x4;

#define WAITV0  asm volatile("s_waitcnt vmcnt(0)" ::: "memory")
#define WAITV8  asm volatile("s_waitcnt vmcnt(8)" ::: "memory")
#define WAITV16 asm volatile("s_waitcnt vmcnt(16)" ::: "memory")

__device__ inline short f2bf(float f) {
    __hip_bfloat16 h = __float2bfloat16(f);
    return *reinterpret_cast<short*>(&h);
}

// ---------------------------------------------------------------------------
// Prep 1: tiled transpose E[256][4096] -> ET32[4096][256] (f32) + ETbf (bf16)
// ---------------------------------------------------------------------------
__global__ void prep_transpose(const float* __restrict__ E,
                               float* __restrict__ ET32,
                               ushort* __restrict__ ETbf)
{
    __shared__ float tile[64][65];
    const int kb = blockIdx.x * 64;
    const int db = blockIdx.y * 64;
    const int lo = threadIdx.x & 63;
    const int hi = threadIdx.x >> 6;

#pragma unroll
    for (int i = 0; i < 16; ++i) {
        int d = i * 4 + hi;
        tile[lo][d] = E[(size_t)(db + d) * KCB + kb + lo];
    }
    __syncthreads();
#pragma unroll
    for (int i = 0; i < 16; ++i) {
        int k = i * 4 + hi;
        float v = tile[k][lo];
        size_t off = (size_t)(kb + k) * DIM + db + lo;
        ET32[off] = v;
        ETbf[off] = (ushort)f2bf(v);
    }
}

// ---------------------------------------------------------------------------
// Prep 2: nenh[k] = -0.5*||e_k||^2 (fp32-exact); score = sim + nenh.
// ---------------------------------------------------------------------------
__global__ void prep_enorm(const float* __restrict__ E, float* __restrict__ nenh)
{
    int k = blockIdx.x * 256 + threadIdx.x;
    float s = 0.0f;
#pragma unroll 8
    for (int d = 0; d < DIM; ++d) {
        float v = E[(size_t)d * KCB + k];
        s = fmaf(v, v, s);
    }
    nenh[k] = -0.5f * s;
}

// ---------------------------------------------------------------------------
// vq_argmin: 2 waves x 64 rows = 128 rows/block; grid 512 = 2 blocks/CU
// (1 wave/SIMD; two INDEPENDENT blocks per CU decorrelate barrier phases on
// the shared LDS pipe). 128 chunks of 32 cols; ring-4 LDS + counted vmcnt;
// register-set double buffer (bA/bB) keeps ds_reads one MFMA-cluster ahead.
// 64 rows/wave doubles B-reuse: LDS-read stream (64KB/CU/chunk ~770cyc) now
// fits under the MFMA stream (1242 cyc) -> MFMA-bound floor.
// LDS map: [0, 64K) ring buffers; [64K, 80K) nenh. 80KB -> 2 blocks/CU.
// ---------------------------------------------------------------------------
__shared__ char lds_raw[NBUF * BUFB + 16384];

// Stage chunk ct (32 cols x 512B = 16KB) into buffer BUF. 2 waves x 8 issues
// x 1KB. LDS dest linear; XOR swizzle (slot ^= col&7) pre-applied to the
// per-lane GLOBAL source offset (both-sides rule, verified R4-R7).
template <int BUF>
__device__ __forceinline__ void stage_chunk(
    const char* __restrict__ etb, const int (&soff)[8], int wave, int ct)
{
    const char* base = etb + (size_t)ct * (CHUNK * 512);
#pragma unroll
    for (int j = 0; j < 8; ++j) {
        __builtin_amdgcn_global_load_lds(
            (const __attribute__((address_space(1))) unsigned*)(base + soff[j]),
            (__attribute__((address_space(3))) unsigned*)
                (lds_raw + BUF * BUFB + wave * 8192 + j * 1024),
            16, 0, 0);
    }
}

// Read one fragment batch: 8x ds_read_b128 (B fragments for a 16-col tile)
// + 1x ds_read_b32 (nh). Buffer offsets fold into the DS imm (max 65520).
template <int BUF, int TC>
__device__ __forceinline__ void read_batch(
    const int (&boffB)[8], int nhbyte, bf16x8 (&bfr)[8], float& nh)
{
#pragma unroll
    for (int kc = 0; kc < 8; ++kc)
        bfr[kc] = *(const bf16x8*)(lds_raw + BUF * BUFB + TC * 8192 + boffB[kc]);
    nh = *(const float*)(lds_raw + NENH_BASE + nhbyte);
}

// 32 MFMA (4 independent acc chains) under setprio + 3-op argmax x16.
// C/D: col = lane&15, row = (lane>>4)*4 + r  [HW-verified]
__device__ __forceinline__ void mfma_cluster(
    const bf16x8 (&afrag)[4][8], const bf16x8 (&bfr)[8], float nh,
    float (&best)[4][4], int (&bidx)[4][4], int col)
{
    f32x4 acc[4];
#pragma unroll
    for (int rt = 0; rt < 4; ++rt) acc[rt] = {nh, nh, nh, nh};
    __builtin_amdgcn_s_setprio(1);
#pragma unroll
    for (int kc = 0; kc < 8; ++kc)
#pragma unroll
        for (int rt = 0; rt < 4; ++rt)
            acc[rt] = __builtin_amdgcn_mfma_f32_16x16x32_bf16(
                afrag[rt][kc], bfr[kc], acc[rt], 0, 0, 0);
    __builtin_amdgcn_s_setprio(0);
#pragma unroll
    for (int rt = 0; rt < 4; ++rt)
#pragma unroll
        for (int r = 0; r < 4; ++r) {
            float s = acc[rt][r];
            bool gt = s > best[rt][r];
            bidx[rt][r] = gt ? col : bidx[rt][r];
            best[rt][r] = fmaxf(best[rt][r], s);
        }
}

// One chunk: WAITV -> barrier -> stage(ct+3) -> R(ct,1)->bB -> MFMA(bA)
// -> R(ct+1,0)->bA -> MFMA(bB). Invariant entering chunk ct: <=16 issues
// outstanding (->ct+1, ->ct+2); WAITV8 retires ->ct+1 (FIFO), so both ct
// (retired one iter earlier) and ct+1 (read-ahead) are LDS-visible after
// the barrier. Stage targets (BUF+3)&3 - disjoint from BUF,(BUF+1)&3 reads.
template <int BUF, int WN, bool STG, bool RA>
__device__ __forceinline__ void chunk_step(
    const char* __restrict__ etb, const int (&soff)[8], int wave, int ct,
    const int (&boffB)[8], int l15,
    const bf16x8 (&afrag)[4][8],
    bf16x8 (&bA)[8], bf16x8 (&bB)[8], float& nhA, float& nhB,
    float (&best)[4][4], int (&bidx)[4][4])
{
    if constexpr (WN == 8) { WAITV8; } else { WAITV0; }
    __builtin_amdgcn_s_barrier();
    __builtin_amdgcn_sched_barrier(0);
    if constexpr (STG) stage_chunk<(BUF + 3) & 3>(etb, soff, wave, ct + 3);
    read_batch<BUF, 1>(boffB, ct * 128 + 64 + l15 * 4, bB, nhB);
    mfma_cluster(afrag, bA, nhA, best, bidx, ct * CHUNK + l15);
    if constexpr (RA)
        read_batch<(BUF + 1) & 3, 0>(boffB, (ct + 1) * 128 + l15 * 4, bA, nhA);
    mfma_cluster(afrag, bB, nhB, best, bidx, ct * CHUNK + 16 + l15);
}

__global__ __launch_bounds__(128, 1)
void vq_argmin(const float* __restrict__ X,       // [65536][256] f32
               const ushort* __restrict__ ETbf,   // [4096][256] bf16
               const float* __restrict__ nenh,    // [4096] = -0.5*||e||^2
               int* __restrict__ idxout)          // [65536]
{
    const int tid  = threadIdx.x;
    const int lane = tid & 63;
    const int wave = tid >> 6;          // 0..1
    const int l15  = lane & 15;
    const int g    = lane >> 4;         // 0..3
    const int m    = l15 & 7;           // read-side swizzle key
    const long rowbase = (long)blockIdx.x * 128 + wave * 64;
    const char* etb = (const char*)ETbf;

    // A fragments resident in VGPRs: lane holds A[row=l15][k=g*64+kc*8+j],
    // rows rowbase + rt*16 + l15, rt = 0..3 (64 rows/wave).
    bf16x8 afrag[4][8];
#pragma unroll
    for (int rt = 0; rt < 4; ++rt) {
        const float* xr = X + (rowbase + rt * 16 + l15) * DIM;
#pragma unroll
        for (int kc = 0; kc < 8; ++kc) {
            int k0 = g * 64 + kc * 8;
            float4 v0 = *(const float4*)(xr + k0);
            float4 v1 = *(const float4*)(xr + k0 + 4);
            bf16x8 f;
            f[0] = f2bf(v0.x); f[1] = f2bf(v0.y);
            f[2] = f2bf(v0.z); f[3] = f2bf(v0.w);
            f[4] = f2bf(v1.x); f[5] = f2bf(v1.y);
            f[6] = f2bf(v1.z); f[7] = f2bf(v1.w);
            afrag[rt][kc] = f;
        }
    }

    // Per-lane global source offsets for staging (XOR-swizzled, as R4-R7).
    int soff[8];
#pragma unroll
    for (int j = 0; j < 8; ++j) {
        const int o    = wave * 8192 + j * 1024 + lane * 16;
        const int col0 = o >> 9;           // 0..31 within chunk
        const int cph  = (o >> 4) & 31;    // physical 16B slot in row
        soff[j] = (col0 << 9) + ((cph ^ (col0 & 7)) << 4);
    }

    // LDS read offsets: row l15 of the 16-col tile, slot (g*8+kc) ^ m.
    int boffB[8];
#pragma unroll
    for (int kc = 0; kc < 8; ++kc)
        boffB[kc] = l15 * 512 + ((((g << 3) + kc) ^ m) << 4);

    // Prologue staging: nenh (16KB, at NENH_BASE; 8 issues/wave) + chunks
    // 0,1,2 (8 issues/wave each) = 32 issues/wave.
#pragma unroll
    for (int j = 0; j < 8; ++j) {
        int o = wave * 8192 + j * 1024 + lane * 16;
        __builtin_amdgcn_global_load_lds(
            (const __attribute__((address_space(1))) unsigned*)((const char*)nenh + o),
            (__attribute__((address_space(3))) unsigned*)
                (lds_raw + NENH_BASE + wave * 8192 + j * 1024),
            16, 0, 0);
    }
    stage_chunk<0>(etb, soff, wave, 0);
    stage_chunk<1>(etb, soff, wave, 1);
    stage_chunk<2>(etb, soff, wave, 2);

    float best[4][4];
    int   bidx[4][4];
#pragma unroll
    for (int rt = 0; rt < 4; ++rt)
#pragma unroll
        for (int r = 0; r < 4; ++r) { best[rt][r] = -3.4e38f; bidx[rt][r] = 0x7fffffff; }

    bf16x8 bA[8], bB[8];
    float nhA, nhB;

    // Prologue wait: retire nenh + chunk0 (leaves chunks 1,2 = 16 in flight).
    WAITV16;
    __builtin_amdgcn_s_barrier();
    __builtin_amdgcn_sched_barrier(0);
    read_batch<0, 0>(boffB, 0 + l15 * 4, bA, nhA);

    for (int gq = 0; gq < 31; ++gq) {
        const int ct = gq * 4;
        chunk_step<0, 8, true, true>(etb, soff, wave, ct + 0, boffB, l15,
                                     afrag, bA, bB, nhA, nhB, best, bidx);
        chunk_step<1, 8, true, true>(etb, soff, wave, ct + 1, boffB, l15,
                                     afrag, bA, bB, nhA, nhB, best, bidx);
        chunk_step<2, 8, true, true>(etb, soff, wave, ct + 2, boffB, l15,
                                     afrag, bA, bB, nhA, nhB, best, bidx);
        chunk_step<3, 8, true, true>(etb, soff, wave, ct + 3, boffB, l15,
                                     afrag, bA, bB, nhA, nhB, best, bidx);
    }
    // Tail: 124 (stages 127), 125, 126 (drain for 127 read-ahead), 127.
    chunk_step<0, 8, true,  true >(etb, soff, wave, 124, boffB, l15,
                                   afrag, bA, bB, nhA, nhB, best, bidx);
    chunk_step<1, 8, false, true >(etb, soff, wave, 125, boffB, l15,
                                   afrag, bA, bB, nhA, nhB, best, bidx);
    chunk_step<2, 0, false, true >(etb, soff, wave, 126, boffB, l15,
                                   afrag, bA, bB, nhA, nhB, best, bidx);
    chunk_step<3, 0, false, false>(etb, soff, wave, 127, boffB, l15,
                                   afrag, bA, bB, nhA, nhB, best, bidx);

    // Reduce across the 16 lanes holding the same row (xor in low 4 bits).
#pragma unroll
    for (int rt = 0; rt < 4; ++rt) {
#pragma unroll
        for (int r = 0; r < 4; ++r) {
            float v = best[rt][r];
            int   ix = bidx[rt][r];
#pragma unroll
            for (int off = 1; off < 16; off <<= 1) {
                float ov = __shfl_xor(v, off, 64);
                int   oi = __shfl_xor(ix, off, 64);
                if (ov > v || (ov == v && oi < ix)) { v = ov; ix = oi; }
            }
            if (l15 == 0) {
                long row = rowbase + rt * 16 + g * 4 + r;
                idxout[row] = ix;
            }
        }
    }
}

// ---------------------------------------------------------------------------
// Gather nearest codebook rows (coalesced from ET32) + histogram
// ---------------------------------------------------------------------------
__global__ void vq_gather(const int* __restrict__ idxin,
                          const float* __restrict__ ET32,
                          float* __restrict__ out,
                          unsigned* __restrict__ counts)
{
    const int tid = threadIdx.x;
    const long n  = (long)blockIdx.x * 4 + (tid >> 6);
    const int d4  = tid & 63;
    const int idx = idxin[n];
    float4 v = *(const float4*)(ET32 + (size_t)idx * DIM + d4 * 4);
    *(float4*)(out + n * DIM + d4 * 4) = v;
    if (d4 == 0) atomicAdd(&counts[idx], 1u);
}

// ---------------------------------------------------------------------------
// Perplexity = exp(-sum p*log(p+1e-10)), p = counts/N
// ---------------------------------------------------------------------------
__global__ void vq_perplexity(const unsigned* __restrict__ counts, float* __restrict__ outp)
{
    __shared__ float wsum[4];
    const int tid = threadIdx.x;
    float s = 0.0f;
    for (int k = tid; k < KCB; k += 256) {
        float p = (float)counts[k] * (1.0f / (float)NROWS);
        s += p * logf(p + 1e-10f);
    }
#pragma unroll
    for (int off = 32; off >= 1; off >>= 1) s += __shfl_down(s, off, 64);
    if ((tid & 63) == 0) wsum[tid >> 6] = s;
    __syncthreads();
    if (tid == 0) outp[0] = expf(-(wsum[0] + wsum[1] + wsum[2] + wsum[3]));
}

// ---------------------------------------------------------------------------
extern "C" void kernel_launch(void* const* d_in, const int* in_sizes, int n_in,
                              void* d_out, int out_size, void* d_ws, size_t ws_size,
                              hipStream_t stream)
{
    const float* X = (const float*)d_in[0];
    const float* E = (const float*)d_in[1];
    float* out = (float*)d_out;

    char* ws = (char*)d_ws;
    float*    ET32   = (float*)ws;                                   // 4 MB
    ushort*   ETbf   = (ushort*)(ws + (size_t)KCB * DIM * 4);        // 2 MB
    float*    nenh   = (float*)(ws + (size_t)KCB * DIM * 6);         // 16 KB
    int*      idxbuf = (int*)(ws + (size_t)KCB * DIM * 6 + KCB * 4); // 256 KB
    unsigned* counts = (unsigned*)(ws + (size_t)KCB * DIM * 6 + KCB * 4 + NROWS * 4); // 16 KB

    hipMemsetAsync(counts, 0, KCB * sizeof(unsigned), stream);

    prep_transpose<<<dim3(KCB / 64, DIM / 64), dim3(256), 0, stream>>>(E, ET32, ETbf);
    prep_enorm<<<KCB / 256, dim3(256), 0, stream>>>(E, nenh);
    vq_argmin<<<NROWS / 128, dim3(128), 0, stream>>>(X, ETbf, nenh, idxbuf);
    vq_gather<<<NROWS / 4, dim3(256), 0, stream>>>(idxbuf, ET32, out, counts);
    vq_perplexity<<<1, dim3(256), 0, stream>>>(counts, out + (size_t)NROWS * DIM);
}